// Round 1
// baseline (8657.003 us; speedup 1.0000x reference)
//
#include <hip/hip_runtime.h>
#include <math.h>

// LSTM fused: B=1024 sequences, S=1024 steps, H=128 hidden, gates 4H=512.
// grid=256 blocks (1/CU), block=512 threads (8 waves), 4 batch elems/block.
// Each thread holds one Wh column (128 fp32) in VGPRs; h broadcast via LDS.

constexpr int Bsz = 1024;
constexpr int Ssz = 1024;
constexpr int Hh  = 128;
constexpr int G4  = 4 * Hh;   // 512 gate columns
constexpr int EPB = 4;        // batch elems per block
constexpr int NT  = 512;      // threads per block

__device__ __forceinline__ float sigmoid_f(float v) {
    return __fdividef(1.0f, 1.0f + __expf(-v));
}
__device__ __forceinline__ float tanh_f(float v) {
    // overflow-safe: use exp(-2|x|) in [0,1]
    float a = fabsf(v);
    float e = __expf(-2.0f * a);
    float r = __fdividef(1.0f - e, 1.0f + e);
    return copysignf(r, v);
}

__global__ __launch_bounds__(NT, 1)
void lstm_fused(const float* __restrict__ x,
                const float* __restrict__ Wi,
                const float* __restrict__ Wh,
                const float* __restrict__ bias,
                const float* __restrict__ Wd,
                const float* __restrict__ bd,
                float* __restrict__ out)
{
    __shared__ float x_lds[EPB * Ssz];     // 16 KB staged input rows
    __shared__ float h_lds[EPB][Hh];       // 2 KB hidden state
    __shared__ float g_lds[EPB][G4];       // 8 KB gate exchange

    const int t  = threadIdx.x;            // = gate column j
    const int b0 = blockIdx.x * EPB;

    // Wh column j = t into registers (coalesced: lane-consecutive j)
    float w[Hh];
    #pragma unroll
    for (int k = 0; k < Hh; ++k) w[k] = Wh[k * G4 + t];
    const float wi = Wi[t];
    const float bj = bias[t];

    // stage x rows for the 4 batch elems (coalesced)
    for (int idx = t; idx < EPB * Ssz; idx += NT) {
        int e = idx >> 10;                 // Ssz == 1024
        int s = idx & (Ssz - 1);
        x_lds[idx] = x[(size_t)(b0 + e) * Ssz + s];
    }
    ((float*)h_lds)[t] = 0.0f;             // EPB*Hh == NT
    float c_st = 0.0f;                     // this thread's (eu,ku) cell state
    float h_st = 0.0f;
    const int gid = t >> 7;                // gate: 0=i 1=f 2=g 3=o (wave-uniform)
    const int eu  = t >> 7;                // update-phase elem
    const int ku  = t & (Hh - 1);          // update-phase hidden unit
    __syncthreads();

    for (int s = 0; s < Ssz; ++s) {
        // xg contribution: x_t * Wi[j] + b[j]
        float a0 = fmaf(x_lds[0 * Ssz + s], wi, bj);
        float a1 = fmaf(x_lds[1 * Ssz + s], wi, bj);
        float a2 = fmaf(x_lds[2 * Ssz + s], wi, bj);
        float a3 = fmaf(x_lds[3 * Ssz + s], wi, bj);

        // h @ Wh column j: broadcast LDS reads, weights in registers
        #pragma unroll
        for (int k = 0; k < Hh; k += 4) {
            const float4 h0 = *(const float4*)(&h_lds[0][k]);
            const float4 h1 = *(const float4*)(&h_lds[1][k]);
            const float4 h2 = *(const float4*)(&h_lds[2][k]);
            const float4 h3 = *(const float4*)(&h_lds[3][k]);
            float hv0[4] = {h0.x, h0.y, h0.z, h0.w};
            float hv1[4] = {h1.x, h1.y, h1.z, h1.w};
            float hv2[4] = {h2.x, h2.y, h2.z, h2.w};
            float hv3[4] = {h3.x, h3.y, h3.z, h3.w};
            #pragma unroll
            for (int q = 0; q < 4; ++q) {
                a0 = fmaf(hv0[q], w[k + q], a0);
                a1 = fmaf(hv1[q], w[k + q], a1);
                a2 = fmaf(hv2[q], w[k + q], a2);
                a3 = fmaf(hv3[q], w[k + q], a3);
            }
        }

        // activation — branch is wave-uniform (gid constant per 2-wave group)
        float v0, v1, v2, v3;
        if (gid == 2) {
            v0 = tanh_f(a0); v1 = tanh_f(a1); v2 = tanh_f(a2); v3 = tanh_f(a3);
        } else {
            v0 = sigmoid_f(a0); v1 = sigmoid_f(a1); v2 = sigmoid_f(a2); v3 = sigmoid_f(a3);
        }
        g_lds[0][t] = v0;
        g_lds[1][t] = v1;
        g_lds[2][t] = v2;
        g_lds[3][t] = v3;
        __syncthreads();   // gates ready; also fences h_lds reads above

        // state update: thread owns (eu, ku)
        float ig = g_lds[eu][0 * Hh + ku];
        float fg = g_lds[eu][1 * Hh + ku];
        float gg = g_lds[eu][2 * Hh + ku];
        float og = g_lds[eu][3 * Hh + ku];
        c_st = fmaf(fg, c_st, ig * gg);
        h_st = og * tanh_f(c_st);
        h_lds[eu][ku] = h_st;
        __syncthreads();   // new h visible for next step
    }

    // epilogue: out[b] = h_final @ Wd + bd
    float p = h_st * Wd[ku];
    ((float*)g_lds)[t] = p;                // index t == eu*Hh + ku
    __syncthreads();
    if (t < EPB) {
        float acc = bd[0];
        for (int k = 0; k < Hh; ++k) acc += ((float*)g_lds)[t * Hh + k];
        out[b0 + t] = acc;
    }
}

extern "C" void kernel_launch(void* const* d_in, const int* in_sizes, int n_in,
                              void* d_out, int out_size, void* d_ws, size_t ws_size,
                              hipStream_t stream) {
    const float* x    = (const float*)d_in[0];
    const float* Wi   = (const float*)d_in[1];
    const float* Wh   = (const float*)d_in[2];
    const float* bias = (const float*)d_in[3];
    const float* Wd   = (const float*)d_in[4];
    const float* bd   = (const float*)d_in[5];
    float* out = (float*)d_out;

    dim3 grid(Bsz / EPB);   // 256
    dim3 block(NT);         // 512
    lstm_fused<<<grid, block, 0, stream>>>(x, Wi, Wh, bias, Wd, bd, out);
}

// Round 2
// 1401.000 us; speedup vs baseline: 6.1792x; 6.1792x over previous
//
#include <hip/hip_runtime.h>
#include <math.h>
#include <stdint.h>

// Fused LSTM via 3-term bf16-compensated MFMA.
// B=1024, S=1024, H=128, gates 4H=512.
// 256 blocks (1/CU) x 512 threads (8 waves). EPB=4 real batch rows of the
// M=16 MFMA tile (rows 4-15 are phantom duplicates - bounded, discarded).
// Wave w owns N-tiles {w, 8+w, 16+w, 24+w} = gates i,f,g,o of units
// [16w,16w+16) -> c-state in registers, no gate exchange. Only h goes
// through LDS (bf16 hi+lo, double-buffered, XOR-swizzled). 1 barrier/step.

constexpr int Bsz = 1024;
constexpr int Ssz = 1024;
constexpr int Hh  = 128;
constexpr int NT  = 512;
constexpr int EPB = 4;

using short8 = __attribute__((ext_vector_type(8))) short;
using f32x4  = __attribute__((ext_vector_type(4))) float;

__device__ __forceinline__ uint16_t bf_rne(float v) {
    uint32_t u = __float_as_uint(v);
    u += 0x7FFFu + ((u >> 16) & 1u);
    return (uint16_t)(u >> 16);
}
__device__ __forceinline__ float bf2f(uint16_t s) {
    return __uint_as_float(((uint32_t)s) << 16);
}
__device__ __forceinline__ float sigm(float x) {
    return __builtin_amdgcn_rcpf(1.0f + __expf(-x));
}
__device__ __forceinline__ float tanh_fast(float x) {
    // 1 - 2/(1+exp(2x)); exp->inf and exp->0 both give correct +/-1 limits
    return 1.0f - 2.0f * __builtin_amdgcn_rcpf(1.0f + __expf(2.0f * x));
}

// LDS row layout for A (h) fragments, per matrix row (256 B of bf16 k=0..127):
// k -> byte = (k>>5)*64 + ((k&15)>>2)*16 + ((k&3) + ((k>>4)&1)*4)*2
// so that lane (q=l>>4) reading ktile kt gets its 8 frag elements as one
// contiguous 16 B chunk at base kt*64 + q*16. Bytes[7:4] XORed with row for
// bank-conflict-free reads (16 lanes x 16 rows -> 16 distinct 16B slots).
__device__ __forceinline__ int kbyte_of_u(int u) {
    return ((u >> 5) << 6) + (((u & 15) >> 2) << 4) + (((u & 3) + ((u >> 4) & 1) * 4) << 1);
}

__global__ __launch_bounds__(NT, 2)
void lstm_mfma(const float* __restrict__ x,  const float* __restrict__ Wi,
               const float* __restrict__ Wh, const float* __restrict__ bias,
               const float* __restrict__ Wd, const float* __restrict__ bd,
               float* __restrict__ out)
{
    __shared__ float    xs[Ssz][EPB];      // 16 KB, x transposed: xs[s][e]
    __shared__ uint16_t Ahi[2][16 * Hh];   // 2 x 4 KB  h hi (bf16), dbuf
    __shared__ uint16_t Alo[2][16 * Hh];   // 2 x 4 KB  h lo (bf16), dbuf
    __shared__ float    red[NT];           // 2 KB epilogue scratch

    const int t  = threadIdx.x;
    const int w  = t >> 6;                 // wave 0..7
    const int l  = t & 63;
    const int q  = l >> 4;                 // quarter-wave group
    const int cl = l & 15;
    const int b0 = blockIdx.x * EPB;

    // ---- stage x transposed (coalesced global, one-time) ----
    for (int i = t; i < EPB * Ssz; i += NT) {
        int e = i >> 10, s = i & (Ssz - 1);
        xs[s][e] = x[(size_t)(b0 + e) * Ssz + s];
    }
    // zero h buffer 0 (h0 = 0)
    {
        uint32_t* p0 = (uint32_t*)&Ahi[0][0];
        uint32_t* p1 = (uint32_t*)&Alo[0][0];
        p0[t] = 0u; p0[t + NT] = 0u;
        p1[t] = 0u; p1[t + NT] = 0u;
    }

    // ---- B fragments: Wh -> bf16 hi/lo, 4 gates x 4 ktiles, in registers ----
    const int u = 16 * w + cl;             // this lane's hidden unit (col in tile)
    short8 Bhi[4][4], Blo[4][4];
    #pragma unroll
    for (int g = 0; g < 4; ++g) {
        const int colabs = g * Hh + u;
        #pragma unroll
        for (int kt = 0; kt < 4; ++kt) {
            #pragma unroll
            for (int j = 0; j < 8; ++j) {
                int k = kt * 32 + ((j >> 2) << 4) + q * 4 + (j & 3);
                float v = Wh[k * 512 + colabs];
                uint16_t hi = bf_rne(v);
                uint16_t lo = bf_rne(v - bf2f(hi));
                Bhi[g][kt][j] = (short)hi;
                Blo[g][kt][j] = (short)lo;
            }
        }
    }
    float wi_g[4], b_g[4];
    #pragma unroll
    for (int g = 0; g < 4; ++g) {
        wi_g[g] = Wi[g * Hh + u];
        b_g[g]  = bias[g * Hh + u];
    }

    // A-frag read offsets (this lane reads matrix row cl), swizzled
    int roff[4];
    #pragma unroll
    for (int kt = 0; kt < 4; ++kt)
        roff[kt] = cl * 256 + ((kt * 64 + q * 16) ^ (cl << 4));
    // h write offsets: this lane owns C rows q*4+r at unit u
    int woff[4];
    #pragma unroll
    for (int r = 0; r < 4; ++r) {
        int rw = q * 4 + r;
        woff[r] = rw * 256 + (kbyte_of_u(u) ^ (rw << 4));
    }

    float cst[4] = {0.f, 0.f, 0.f, 0.f};
    __syncthreads();

    for (int s = 0; s < Ssz; ++s) {
        const char* Ah = (const char*)&Ahi[s & 1][0];
        const char* Al = (const char*)&Alo[s & 1][0];
        short8 ah[4], al[4];
        #pragma unroll
        for (int kt = 0; kt < 4; ++kt) {
            ah[kt] = *(const short8*)(Ah + roff[kt]);
            al[kt] = *(const short8*)(Al + roff[kt]);
        }
        f32x4 acc[4];
        #pragma unroll
        for (int g = 0; g < 4; ++g) acc[g] = (f32x4){0.f, 0.f, 0.f, 0.f};
        // term 1: A_hi * B_hi   (dep distance 4 on each acc[g])
        #pragma unroll
        for (int kt = 0; kt < 4; ++kt)
            #pragma unroll
            for (int g = 0; g < 4; ++g)
                acc[g] = __builtin_amdgcn_mfma_f32_16x16x32_bf16(ah[kt], Bhi[g][kt], acc[g], 0, 0, 0);
        // term 2: A_lo * B_hi
        #pragma unroll
        for (int kt = 0; kt < 4; ++kt)
            #pragma unroll
            for (int g = 0; g < 4; ++g)
                acc[g] = __builtin_amdgcn_mfma_f32_16x16x32_bf16(al[kt], Bhi[g][kt], acc[g], 0, 0, 0);
        // term 3: A_hi * B_lo
        #pragma unroll
        for (int kt = 0; kt < 4; ++kt)
            #pragma unroll
            for (int g = 0; g < 4; ++g)
                acc[g] = __builtin_amdgcn_mfma_f32_16x16x32_bf16(ah[kt], Blo[g][kt], acc[g], 0, 0, 0);

        const float4 xv = *(const float4*)&xs[s][0];   // broadcast read
        float xr[4] = {xv.x, xv.y, xv.z, xv.w};
        uint16_t* An_h = &Ahi[(s + 1) & 1][0];
        uint16_t* An_l = &Alo[(s + 1) & 1][0];
        #pragma unroll
        for (int r = 0; r < 4; ++r) {
            float pi = acc[0][r] + xr[r] * wi_g[0] + b_g[0];
            float pf = acc[1][r] + xr[r] * wi_g[1] + b_g[1];
            float pg = acc[2][r] + xr[r] * wi_g[2] + b_g[2];
            float po = acc[3][r] + xr[r] * wi_g[3] + b_g[3];
            float ig = sigm(pi);
            float fg = sigm(pf);
            float gg = tanh_fast(pg);
            float og = sigm(po);
            cst[r] = fmaf(fg, cst[r], ig * gg);
            float h = og * tanh_fast(cst[r]);
            uint16_t hi = bf_rne(h);
            uint16_t lo = bf_rne(h - bf2f(hi));
            *(uint16_t*)((char*)An_h + woff[r]) = hi;
            *(uint16_t*)((char*)An_l + woff[r]) = lo;
        }
        __syncthreads();   // writes of buf (s+1)&1 done; next iter reads it
    }

    // ---- epilogue: out[b] = h_final @ Wd + bd ; final h in buf 0 (S even) ----
    {
        int e = t >> 7, uu = t & 127;
        int off = e * 256 + (kbyte_of_u(uu) ^ (e << 4));
        float h = bf2f(*(uint16_t*)((char*)&Ahi[0][0] + off))
                + bf2f(*(uint16_t*)((char*)&Alo[0][0] + off));
        red[t] = h * Wd[uu];
    }
    __syncthreads();
    if (t < EPB) {
        float acc = bd[0];
        for (int k = 0; k < Hh; ++k) acc += red[t * Hh + k];
        out[b0 + t] = acc;
    }
}

extern "C" void kernel_launch(void* const* d_in, const int* in_sizes, int n_in,
                              void* d_out, int out_size, void* d_ws, size_t ws_size,
                              hipStream_t stream) {
    const float* x    = (const float*)d_in[0];
    const float* Wi   = (const float*)d_in[1];
    const float* Wh   = (const float*)d_in[2];
    const float* bias = (const float*)d_in[3];
    const float* Wd   = (const float*)d_in[4];
    const float* bd   = (const float*)d_in[5];
    float* out = (float*)d_out;

    lstm_mfma<<<dim3(Bsz / EPB), dim3(NT), 0, stream>>>(x, Wi, Wh, bias, Wd, bd, out);
}

// Round 3
// 1139.433 us; speedup vs baseline: 7.5976x; 1.2296x over previous
//
#include <hip/hip_runtime.h>
#include <math.h>
#include <stdint.h>

// Fused LSTM via 3-term bf16-compensated MFMA, v2.
// B=1024, S=1024, H=128, gates 4H=512.
// 256 blocks (1/CU) x 512 threads (8 waves).
// M=16 MFMA tile; the 4 REAL batch rows sit at tile rows {0,4,8,12} so that
// (C-layout: row=(lane>>4)*4+reg) every lane's acc[g][0] holds the 4 gates of
// its own (elem=q, unit=16w+cl) -> activations are 1 gate-set/thread, no
// redistribution, no phantom activation work. A-rows other than {0,4,8,12}
// stay zero forever -> A-fragment LDS reads exec-masked to cl%4==0 lanes.

constexpr int Bsz = 1024;
constexpr int Ssz = 1024;
constexpr int Hh  = 128;
constexpr int NT  = 512;
constexpr int EPB = 4;

using short8 = __attribute__((ext_vector_type(8))) short;
using f32x4  = __attribute__((ext_vector_type(4))) float;

__device__ __forceinline__ uint16_t bf_rne(float v) {
    uint32_t u = __float_as_uint(v);
    u += 0x7FFFu + ((u >> 16) & 1u);
    return (uint16_t)(u >> 16);
}
__device__ __forceinline__ float bf2f(uint16_t s) {
    return __uint_as_float(((uint32_t)s) << 16);
}
__device__ __forceinline__ float sigm(float x) {
    return __builtin_amdgcn_rcpf(1.0f + __expf(-x));
}
__device__ __forceinline__ float tanh_fast(float x) {
    // tanh(x) = 1 - 2/(1+exp(2x)); exp->inf / ->0 give correct +/-1 limits
    return 1.0f - 2.0f * __builtin_amdgcn_rcpf(1.0f + __expf(2.0f * x));
}

// Logical byte offset of k within a 256 B A-row (fragment-contiguous layout):
// lane (q,cl) reading ktile kt gets its short8 at logical kt*64 + q*16.
__device__ __forceinline__ int kbyte_of_u(int k) {
    return ((k >> 5) << 6) + (((k & 15) >> 2) << 4) + (((k & 3) + ((k >> 4) & 1) * 4) << 1);
}
// Physical = row*256 + ((logical + row*16) & 255): rotates each row's phase
// so the 16 active reader lanes hit 16 distinct 16B slots (2-way = free).

__global__ __launch_bounds__(NT, 2)
void lstm_mfma2(const float* __restrict__ x,  const float* __restrict__ Wi,
                const float* __restrict__ Wh, const float* __restrict__ bias,
                const float* __restrict__ Wd, const float* __restrict__ bd,
                float* __restrict__ out)
{
    __shared__ float xs[Ssz][EPB];                       // 16 KB x transposed
    __shared__ __align__(16) uint16_t Ahi[2][16 * Hh];   // 2x4 KB h hi, dbuf
    __shared__ __align__(16) uint16_t Alo[2][16 * Hh];   // 2x4 KB h lo, dbuf
    __shared__ float red[NT];                            // 2 KB epilogue

    const int t  = threadIdx.x;
    const int w  = t >> 6;
    const int l  = t & 63;
    const int q  = l >> 4;
    const int cl = l & 15;
    const int b0 = blockIdx.x * EPB;

    // stage x transposed (coalesced, one-time)
    for (int i = t; i < EPB * Ssz; i += NT) {
        int e = i >> 10, s = i & (Ssz - 1);
        xs[s][e] = x[(size_t)(b0 + e) * Ssz + s];
    }
    // zero both A buffers entirely (rows != {0,4,8,12} stay zero forever)
    {
        uint32_t* pa = (uint32_t*)Ahi;
        uint32_t* pb = (uint32_t*)Alo;
        for (int i = t; i < 2048; i += NT) { pa[i] = 0u; pb[i] = 0u; }
    }

    // B fragments: Wh -> bf16 hi/lo, 4 gates x 4 ktiles, in registers
    const int u = 16 * w + cl;             // this lane's hidden unit
    short8 Bhi[4][4], Blo[4][4];
    #pragma unroll
    for (int g = 0; g < 4; ++g) {
        const int colabs = g * Hh + u;
        #pragma unroll
        for (int kt = 0; kt < 4; ++kt) {
            #pragma unroll
            for (int j = 0; j < 8; ++j) {
                int k = kt * 32 + ((j >> 2) << 4) + q * 4 + (j & 3);
                float v = Wh[k * 512 + colabs];
                uint16_t hi = bf_rne(v);
                uint16_t lo = bf_rne(v - bf2f(hi));
                Bhi[g][kt][j] = (short)hi;
                Blo[g][kt][j] = (short)lo;
            }
        }
    }
    float wi_g[4], b_g[4];
    #pragma unroll
    for (int g = 0; g < 4; ++g) {
        wi_g[g] = Wi[g * Hh + u];
        b_g[g]  = bias[g * Hh + u];
    }

    // A-frag read offsets: lane reads matrix row cl (nonzero only if cl%4==0)
    int roff[4];
    #pragma unroll
    for (int kt = 0; kt < 4; ++kt)
        roff[kt] = cl * 256 + ((kt * 64 + q * 16 + cl * 16) & 255);
    const bool aload = ((cl & 3) == 0);
    // h write offset: this thread owns (elem=q, unit=u) -> A row 4q
    const int woff = (q * 4) * 256 + ((kbyte_of_u(u) + q * 64) & 255);

    float cst = 0.f, h_st = 0.f;
    __syncthreads();

    for (int s = 0; s < Ssz; ++s) {
        const char* Ah = (const char*)&Ahi[s & 1][0];
        const char* Al = (const char*)&Alo[s & 1][0];
        short8 ah[4], al[4];
        #pragma unroll
        for (int kt = 0; kt < 4; ++kt) {
            ah[kt] = (short8){0,0,0,0,0,0,0,0};
            al[kt] = (short8){0,0,0,0,0,0,0,0};
        }
        if (aload) {
            #pragma unroll
            for (int kt = 0; kt < 4; ++kt) {
                ah[kt] = *(const short8*)(Ah + roff[kt]);
                al[kt] = *(const short8*)(Al + roff[kt]);
            }
        }
        f32x4 acc[4];
        #pragma unroll
        for (int g = 0; g < 4; ++g) acc[g] = (f32x4){0.f, 0.f, 0.f, 0.f};
        #pragma unroll
        for (int kt = 0; kt < 4; ++kt)
            #pragma unroll
            for (int g = 0; g < 4; ++g)
                acc[g] = __builtin_amdgcn_mfma_f32_16x16x32_bf16(ah[kt], Bhi[g][kt], acc[g], 0, 0, 0);
        #pragma unroll
        for (int kt = 0; kt < 4; ++kt)
            #pragma unroll
            for (int g = 0; g < 4; ++g)
                acc[g] = __builtin_amdgcn_mfma_f32_16x16x32_bf16(al[kt], Bhi[g][kt], acc[g], 0, 0, 0);
        #pragma unroll
        for (int kt = 0; kt < 4; ++kt)
            #pragma unroll
            for (int g = 0; g < 4; ++g)
                acc[g] = __builtin_amdgcn_mfma_f32_16x16x32_bf16(ah[kt], Blo[g][kt], acc[g], 0, 0, 0);

        // this thread's gate pre-activations: acc[g][0] (tile row 4q = elem q)
        const float xv = xs[s][q];
        float pi = acc[0][0] + fmaf(xv, wi_g[0], b_g[0]);
        float pf = acc[1][0] + fmaf(xv, wi_g[1], b_g[1]);
        float pg = acc[2][0] + fmaf(xv, wi_g[2], b_g[2]);
        float po = acc[3][0] + fmaf(xv, wi_g[3], b_g[3]);
        float ig = sigm(pi);
        float fg = sigm(pf);
        float gg = tanh_fast(pg);
        float og = sigm(po);
        cst  = fmaf(fg, cst, ig * gg);
        h_st = og * tanh_fast(cst);
        uint16_t hi = bf_rne(h_st);
        uint16_t lo = bf_rne(h_st - bf2f(hi));
        *(uint16_t*)((char*)&Ahi[(s + 1) & 1][0] + woff) = hi;
        *(uint16_t*)((char*)&Alo[(s + 1) & 1][0] + woff) = lo;
        __syncthreads();
    }

    // epilogue: out[b] = h_final @ Wd + bd (h_final lives in registers)
    red[q * Hh + u] = h_st * Wd[u];
    __syncthreads();
    if (t < EPB) {
        float acc = bd[0];
        for (int k = 0; k < Hh; ++k) acc += red[t * Hh + k];
        out[b0 + t] = acc;
    }
}

extern "C" void kernel_launch(void* const* d_in, const int* in_sizes, int n_in,
                              void* d_out, int out_size, void* d_ws, size_t ws_size,
                              hipStream_t stream) {
    const float* x    = (const float*)d_in[0];
    const float* Wi   = (const float*)d_in[1];
    const float* Wh   = (const float*)d_in[2];
    const float* bias = (const float*)d_in[3];
    const float* Wd   = (const float*)d_in[4];
    const float* bd   = (const float*)d_in[5];
    float* out = (float*)d_out;

    lstm_mfma2<<<dim3(Bsz / EPB), dim3(NT), 0, stream>>>(x, Wi, Wh, bias, Wd, bd, out);
}

// Round 4
// 1043.551 us; speedup vs baseline: 8.2957x; 1.0919x over previous
//
#include <hip/hip_runtime.h>
#include <math.h>
#include <stdint.h>

// Fused LSTM via 3-term bf16-compensated MFMA, v3.
// B=1024, S=1024, H=128, gates 4H=512.
// 256 blocks (1/CU) x 512 threads (8 waves).
// Real batch rows at tile rows {0,4,8,12}: each lane's acc[g][0] is its own
// (elem=q, unit=16w+cl) gate pre-activation. A-rows other than {0,4,8,12}
// stay zero; only lanes cl%4==0 read A fragments from LDS.
// v3: ah/al zero-init hoisted out of the step loop; accumulator chains start
// from a shared zero C-init register (no per-step acc movs); 2 chains/gate.

constexpr int Bsz = 1024;
constexpr int Ssz = 1024;
constexpr int Hh  = 128;
constexpr int NT  = 512;
constexpr int EPB = 4;

using short8 = __attribute__((ext_vector_type(8))) short;
using f32x4  = __attribute__((ext_vector_type(4))) float;

__device__ __forceinline__ uint16_t bf_rne(float v) {
    uint32_t u = __float_as_uint(v);
    u += 0x7FFFu + ((u >> 16) & 1u);
    return (uint16_t)(u >> 16);
}
__device__ __forceinline__ float bf2f(uint16_t s) {
    return __uint_as_float(((uint32_t)s) << 16);
}
__device__ __forceinline__ float sigm(float x) {
    return __builtin_amdgcn_rcpf(1.0f + __expf(-x));
}
__device__ __forceinline__ float tanh_fast(float x) {
    // tanh(x) = 1 - 2/(1+exp(2x)); exp->inf / ->0 give correct +/-1 limits
    return 1.0f - 2.0f * __builtin_amdgcn_rcpf(1.0f + __expf(2.0f * x));
}

// Logical byte offset of k within a 256 B A-row (fragment-contiguous layout).
__device__ __forceinline__ int kbyte_of_u(int k) {
    return ((k >> 5) << 6) + (((k & 15) >> 2) << 4) + (((k & 3) + ((k >> 4) & 1) * 4) << 1);
}

__global__ __launch_bounds__(NT, 2)
void lstm_mfma3(const float* __restrict__ x,  const float* __restrict__ Wi,
                const float* __restrict__ Wh, const float* __restrict__ bias,
                const float* __restrict__ Wd, const float* __restrict__ bd,
                float* __restrict__ out)
{
    __shared__ float xs[Ssz][EPB];                       // 16 KB x transposed
    __shared__ __align__(16) uint16_t Ahi[2][16 * Hh];   // 2x4 KB h hi, dbuf
    __shared__ __align__(16) uint16_t Alo[2][16 * Hh];   // 2x4 KB h lo, dbuf
    __shared__ float red[NT];                            // 2 KB epilogue

    const int t  = threadIdx.x;
    const int w  = t >> 6;
    const int l  = t & 63;
    const int q  = l >> 4;
    const int cl = l & 15;
    const int b0 = blockIdx.x * EPB;

    // stage x transposed (coalesced, one-time)
    for (int i = t; i < EPB * Ssz; i += NT) {
        int e = i >> 10, s = i & (Ssz - 1);
        xs[s][e] = x[(size_t)(b0 + e) * Ssz + s];
    }
    // zero A buffers (rows != {0,4,8,12} stay zero forever)
    {
        uint32_t* pa = (uint32_t*)Ahi;
        uint32_t* pb = (uint32_t*)Alo;
        for (int i = t; i < 2048; i += NT) { pa[i] = 0u; pb[i] = 0u; }
    }

    // B fragments: Wh -> bf16 hi/lo, 4 gates x 4 ktiles, in registers
    const int u = 16 * w + cl;             // this lane's hidden unit
    short8 Bhi[4][4], Blo[4][4];
    #pragma unroll
    for (int g = 0; g < 4; ++g) {
        const int colabs = g * Hh + u;
        #pragma unroll
        for (int kt = 0; kt < 4; ++kt) {
            #pragma unroll
            for (int j = 0; j < 8; ++j) {
                int k = kt * 32 + ((j >> 2) << 4) + q * 4 + (j & 3);
                float v = Wh[k * 512 + colabs];
                uint16_t hi = bf_rne(v);
                uint16_t lo = bf_rne(v - bf2f(hi));
                Bhi[g][kt][j] = (short)hi;
                Blo[g][kt][j] = (short)lo;
            }
        }
    }
    float wi_g[4], b_g[4];
    #pragma unroll
    for (int g = 0; g < 4; ++g) {
        wi_g[g] = Wi[g * Hh + u];
        b_g[g]  = bias[g * Hh + u];
    }

    // A-frag read offsets (row cl, phase-rotated per row: conflict-free)
    int roff[4];
    #pragma unroll
    for (int kt = 0; kt < 4; ++kt)
        roff[kt] = cl * 256 + ((kt * 64 + q * 16 + cl * 16) & 255);
    const bool aload = ((cl & 3) == 0);
    const int woff = (q * 4) * 256 + ((kbyte_of_u(u) + q * 64) & 255);

    // A fragments: zero ONCE (non-aload lanes keep zeros for all 1024 steps)
    short8 ah[4], al[4];
    #pragma unroll
    for (int kt = 0; kt < 4; ++kt) {
        ah[kt] = (short8){0,0,0,0,0,0,0,0};
        al[kt] = (short8){0,0,0,0,0,0,0,0};
    }
    // shared C-init (consumed, never written - MFMA dest is written fresh)
    f32x4 zv = (f32x4){0.f, 0.f, 0.f, 0.f};

    float cst = 0.f, h_st = 0.f;
    __syncthreads();

    for (int s = 0; s < Ssz; ++s) {
        const char* Ah = (const char*)&Ahi[s & 1][0];
        const char* Al = (const char*)&Alo[s & 1][0];
        if (aload) {
            #pragma unroll
            for (int kt = 0; kt < 4; ++kt) {
                ah[kt] = *(const short8*)(Ah + roff[kt]);
                al[kt] = *(const short8*)(Al + roff[kt]);
            }
        }
        // chain A: terms (A_hi*B_hi) then (A_lo*B_hi), 8 deep
        // chain B: term (A_hi*B_lo), 4 deep        -> 8 indep chains/wave
        f32x4 ca[4], cb[4];
        #pragma unroll
        for (int g = 0; g < 4; ++g)
            ca[g] = __builtin_amdgcn_mfma_f32_16x16x32_bf16(ah[0], Bhi[g][0], zv, 0, 0, 0);
        #pragma unroll
        for (int g = 0; g < 4; ++g)
            cb[g] = __builtin_amdgcn_mfma_f32_16x16x32_bf16(ah[0], Blo[g][0], zv, 0, 0, 0);
        #pragma unroll
        for (int kt = 1; kt < 4; ++kt) {
            #pragma unroll
            for (int g = 0; g < 4; ++g)
                ca[g] = __builtin_amdgcn_mfma_f32_16x16x32_bf16(ah[kt], Bhi[g][kt], ca[g], 0, 0, 0);
            #pragma unroll
            for (int g = 0; g < 4; ++g)
                cb[g] = __builtin_amdgcn_mfma_f32_16x16x32_bf16(ah[kt], Blo[g][kt], cb[g], 0, 0, 0);
        }
        #pragma unroll
        for (int kt = 0; kt < 4; ++kt)
            #pragma unroll
            for (int g = 0; g < 4; ++g)
                ca[g] = __builtin_amdgcn_mfma_f32_16x16x32_bf16(al[kt], Bhi[g][kt], ca[g], 0, 0, 0);

        const float xv = xs[s][q];
        float pi = ca[0][0] + (cb[0][0] + fmaf(xv, wi_g[0], b_g[0]));
        float pf = ca[1][0] + (cb[1][0] + fmaf(xv, wi_g[1], b_g[1]));
        float pg = ca[2][0] + (cb[2][0] + fmaf(xv, wi_g[2], b_g[2]));
        float po = ca[3][0] + (cb[3][0] + fmaf(xv, wi_g[3], b_g[3]));
        float ig = sigm(pi);
        float fg = sigm(pf);
        float gg = tanh_fast(pg);
        float og = sigm(po);
        cst  = fmaf(fg, cst, ig * gg);
        h_st = og * tanh_fast(cst);
        uint16_t hi = bf_rne(h_st);
        uint16_t lo = bf_rne(h_st - bf2f(hi));
        *(uint16_t*)((char*)&Ahi[(s + 1) & 1][0] + woff) = hi;
        *(uint16_t*)((char*)&Alo[(s + 1) & 1][0] + woff) = lo;
        __syncthreads();
    }

    // epilogue: out[b] = h_final @ Wd + bd (h_final in registers)
    red[q * Hh + u] = h_st * Wd[u];
    __syncthreads();
    if (t < EPB) {
        float acc = bd[0];
        for (int k = 0; k < Hh; ++k) acc += red[t * Hh + k];
        out[b0 + t] = acc;
    }
}

extern "C" void kernel_launch(void* const* d_in, const int* in_sizes, int n_in,
                              void* d_out, int out_size, void* d_ws, size_t ws_size,
                              hipStream_t stream) {
    const float* x    = (const float*)d_in[0];
    const float* Wi   = (const float*)d_in[1];
    const float* Wh   = (const float*)d_in[2];
    const float* bias = (const float*)d_in[3];
    const float* Wd   = (const float*)d_in[4];
    const float* bd   = (const float*)d_in[5];
    float* out = (float*)d_out;

    lstm_mfma3<<<dim3(Bsz / EPB), dim3(NT), 0, stream>>>(x, Wi, Wh, bias, Wd, bd, out);
}